// Round 5
// baseline (548.837 us; speedup 1.0000x reference)
//
#include <hip/hip_runtime.h>
#include <hip/hip_bf16.h>
#include <stdint.h>

// LocalEnhancementModule on MI355X (gfx950).
// B=16 C=16 H=W=256 NP=16 -> P=256, D=4096, E=512, M=B*P=4096.
//  prep_pw : x -> p_hi/p_lo bf16 [M,D]  +  [theta_w|f_w] -> w hi/lo [1024,D]
//  gemm1f  : fused 3-product hi/lo bf16 MFMA, split-K x3 (768 blocks = 3/CU)
//            -> C1a/C1b/C1c fp32 [M,1024] (swapped: A=w rows -> float4 C-stores)
//  combine_prepg : C1a+C1b+C1c+bias -> thf hi/lo bf16; also g_w -> gwt bf16
//  scores  : 3-pass hi/lo MFMA theta@f^T -> S fp32 [16,256,256]
//  softmax_rows : in-place row softmax on S
//  gemm2   : bf16 MFMA, A=gwt rows, B=pHi rows; float4 epilogue
//            out = scale*w*(acc+g_b) + x
//
// Workspace (lifetime-packed, max 128 MiB):
//  pHi [0,32) | pLo->gwt [32,64) | wHi/wLo [64,80) -> thfHi/thfLo after gemm1f
//  C1a->S [80,96) | C1b [96,112) | C1c [112,128)

typedef __hip_bfloat16 bf16;
typedef __bf16 bf16x8 __attribute__((ext_vector_type(8)));
typedef float f32x4 __attribute__((ext_vector_type(4)));

#define GLOBAL_AS __attribute__((address_space(1)))
#define LDS_AS __attribute__((address_space(3)))

__device__ __forceinline__ void gload_lds16(const void* g, void* l) {
    void* gg = const_cast<void*>(g);
    __builtin_amdgcn_global_load_lds((GLOBAL_AS void*)gg, (LDS_AS void*)l, 16, 0, 0);
}

// ---------------- merged prep: p (hi/lo) + w (hi/lo transposed) ----------------

__global__ __launch_bounds__(256) void prep_pw(const float* __restrict__ x,
                                               const float* __restrict__ theta_w,
                                               const float* __restrict__ f_w,
                                               bf16* __restrict__ pHi,
                                               bf16* __restrict__ pLo,
                                               bf16* __restrict__ wHi,
                                               bf16* __restrict__ wLo) {
    __shared__ float tile[32][33];
    int blk = blockIdx.x;
    if (blk < 16384) {
        int tid = blk * 256 + threadIdx.x;           // over [B][C][H][W/4]
        int w4 = tid & 63;
        int h  = (tid >> 6) & 255;
        int c  = (tid >> 14) & 15;
        int b  = tid >> 18;
        float4 v = ((const float4*)x)[tid];
        int i = h >> 4, y = h & 15, j = w4 >> 2, zb = (w4 & 3) * 4;
        int m = b * 256 + i * 16 + j;
        int k = c * 256 + y * 16 + zb;
        size_t o = (size_t)m * 4096 + k;
        float vs[4] = {v.x, v.y, v.z, v.w};
#pragma unroll
        for (int q = 0; q < 4; ++q) {
            bf16 hv = __float2bfloat16(vs[q]);
            float rem = vs[q] - __bfloat162float(hv);
            pHi[o + q] = hv;
            pLo[o + q] = __float2bfloat16(rem);
        }
    } else {
        int bid = blk - 16384;                       // 4096 blocks
        int t = threadIdx.x;
        int tx = t & 31, ty = t >> 5;
        int k0 = (bid & 127) * 32;
        int e0 = (bid >> 7) * 32;
#pragma unroll
        for (int r = 0; r < 4; ++r) {
            int k = k0 + ty + r * 8;
            int e = e0 + tx;
            float v = (e < 512) ? theta_w[(size_t)k * 512 + e]
                                : f_w[(size_t)k * 512 + (e - 512)];
            tile[ty + r * 8][tx] = v;
        }
        __syncthreads();
#pragma unroll
        for (int r = 0; r < 4; ++r) {
            int e = e0 + ty + r * 8;
            int k = k0 + tx;
            float v = tile[tx][ty + r * 8];
            bf16 hv = __float2bfloat16(v);
            float rem = v - __bfloat162float(hv);
            wHi[(size_t)e * 4096 + k] = hv;
            wLo[(size_t)e * 4096 + k] = __float2bfloat16(rem);
        }
    }
}

// ---------------- generic GEMM pass (scores / gemm2) ----------------
// BM=BN=128, BK=32, 256 threads (4 waves, 2x2 wave grid, 64x64/wave).
__device__ __forceinline__ void gemm_pass(const bf16* A, const bf16* Bt,
                                          int lda, int ldb, int m0, int n0,
                                          int kbase, int ksteps,
                                          bf16* As, bf16* Bs, f32x4 (&acc)[4][4]) {
    int t = threadIdx.x, lane = t & 63, wave = t >> 6;
    int wm = wave & 1, wn = wave >> 1;
    int lr = lane & 15, lq = lane >> 4;
    const bf16* gA = A + (size_t)m0 * lda;
    const bf16* gB = Bt + (size_t)n0 * ldb;
    int chunk0 = wave * 2;
    int srow0 = lane >> 2;
    int cb = (lane & 3) * 16;
    for (int ks = 0; ks < ksteps; ++ks) {
        int kt = kbase + ks * 32;
#pragma unroll
        for (int tt = 0; tt < 2; ++tt) {
            int chunk = chunk0 + tt;
            int row = chunk * 16 + srow0;
            gload_lds16((const char*)(gA + ((size_t)row * lda + kt)) + cb,
                        (char*)As + chunk * 1024);
            gload_lds16((const char*)(gB + ((size_t)row * ldb + kt)) + cb,
                        (char*)Bs + chunk * 1024);
        }
        __syncthreads();
        bf16x8 af[4], bfr[4];
#pragma unroll
        for (int mt = 0; mt < 4; ++mt)
            af[mt] = *(const bf16x8*)((const char*)As + (wm * 64 + mt * 16 + lr) * 64 + lq * 16);
#pragma unroll
        for (int nt = 0; nt < 4; ++nt)
            bfr[nt] = *(const bf16x8*)((const char*)Bs + (wn * 64 + nt * 16 + lr) * 64 + lq * 16);
#pragma unroll
        for (int mt = 0; mt < 4; ++mt)
#pragma unroll
            for (int nt = 0; nt < 4; ++nt)
                acc[mt][nt] = __builtin_amdgcn_mfma_f32_16x16x32_bf16(
                    af[mt], bfr[nt], acc[mt][nt], 0, 0, 0);
        __syncthreads();
    }
}

// ---------------- gemm1f: fused 3-product hi/lo, split-K x3, swapped ----------------
// A = w rows (e-dim, 1024), B = p rows (patch dim, 4096).

__global__ __launch_bounds__(256, 3) void gemm1f(const bf16* __restrict__ pHi,
                                                 const bf16* __restrict__ pLo,
                                                 const bf16* __restrict__ wHi,
                                                 const bf16* __restrict__ wLo,
                                                 float* __restrict__ C1a,
                                                 float* __restrict__ C1b,
                                                 float* __restrict__ C1c) {
    __shared__ bf16 AsHi[128 * 32];
    __shared__ bf16 AsLo[128 * 32];
    __shared__ bf16 BsHi[128 * 32];
    __shared__ bf16 BsLo[128 * 32];
    int m0 = blockIdx.x * 128;      // e-dim
    int n0 = blockIdx.y * 128;      // patch dim
    int z = blockIdx.z;
    int kbase = z * 43 * 32;
    int ksteps = (z == 2) ? 42 : 43;
    int t = threadIdx.x, lane = t & 63, wave = t >> 6;
    int wm = wave & 1, wn = wave >> 1;
    int lr = lane & 15, lq = lane >> 4;
    const bf16* gAh = wHi + (size_t)m0 * 4096;
    const bf16* gAl = wLo + (size_t)m0 * 4096;
    const bf16* gBh = pHi + (size_t)n0 * 4096;
    const bf16* gBl = pLo + (size_t)n0 * 4096;
    int chunk0 = wave * 2;
    int srow0 = lane >> 2;
    int cb = (lane & 3) * 16;
    f32x4 acc[4][4] = {};
    for (int ks = 0; ks < ksteps; ++ks) {
        int kt = kbase + ks * 32;
#pragma unroll
        for (int tt = 0; tt < 2; ++tt) {
            int chunk = chunk0 + tt;
            size_t off = (size_t)(chunk * 16 + srow0) * 4096 + kt;
            gload_lds16((const char*)(gAh + off) + cb, (char*)AsHi + chunk * 1024);
            gload_lds16((const char*)(gAl + off) + cb, (char*)AsLo + chunk * 1024);
            gload_lds16((const char*)(gBh + off) + cb, (char*)BsHi + chunk * 1024);
            gload_lds16((const char*)(gBl + off) + cb, (char*)BsLo + chunk * 1024);
        }
        __syncthreads();
        bf16x8 ah[4], al[4], bh[4], bl[4];
#pragma unroll
        for (int mt = 0; mt < 4; ++mt) {
            int ro = (wm * 64 + mt * 16 + lr) * 64 + lq * 16;
            ah[mt] = *(const bf16x8*)((const char*)AsHi + ro);
            al[mt] = *(const bf16x8*)((const char*)AsLo + ro);
        }
#pragma unroll
        for (int nt = 0; nt < 4; ++nt) {
            int ro = (wn * 64 + nt * 16 + lr) * 64 + lq * 16;
            bh[nt] = *(const bf16x8*)((const char*)BsHi + ro);
            bl[nt] = *(const bf16x8*)((const char*)BsLo + ro);
        }
#pragma unroll
        for (int mt = 0; mt < 4; ++mt)
#pragma unroll
            for (int nt = 0; nt < 4; ++nt)
                acc[mt][nt] = __builtin_amdgcn_mfma_f32_16x16x32_bf16(
                    ah[mt], bl[nt], acc[mt][nt], 0, 0, 0);
#pragma unroll
        for (int mt = 0; mt < 4; ++mt)
#pragma unroll
            for (int nt = 0; nt < 4; ++nt)
                acc[mt][nt] = __builtin_amdgcn_mfma_f32_16x16x32_bf16(
                    al[mt], bh[nt], acc[mt][nt], 0, 0, 0);
#pragma unroll
        for (int mt = 0; mt < 4; ++mt)
#pragma unroll
            for (int nt = 0; nt < 4; ++nt)
                acc[mt][nt] = __builtin_amdgcn_mfma_f32_16x16x32_bf16(
                    ah[mt], bh[nt], acc[mt][nt], 0, 0, 0);
        __syncthreads();
    }
    float* C = (z == 0) ? C1a : (z == 1) ? C1b : C1c;
#pragma unroll
    for (int mt = 0; mt < 4; ++mt) {
        int e = m0 + wm * 64 + mt * 16 + lq * 4;       // +reg, 4-consecutive
#pragma unroll
        for (int nt = 0; nt < 4; ++nt) {
            int p = n0 + wn * 64 + nt * 16 + lr;
            *(float4*)(C + (size_t)p * 1024 + e) = *(float4*)&acc[mt][nt];
        }
    }
}

// ---------------- combine + prep_g merged ----------------

__global__ __launch_bounds__(256) void combine_prepg(const float* __restrict__ C1a,
                                                     const float* __restrict__ C1b,
                                                     const float* __restrict__ C1c,
                                                     const float* __restrict__ theta_b,
                                                     const float* __restrict__ f_b,
                                                     const float* __restrict__ g_w,
                                                     bf16* __restrict__ thfHi,
                                                     bf16* __restrict__ thfLo,
                                                     bf16* __restrict__ gwt) {
    __shared__ float tile[32][33];
    int blk = blockIdx.x;
    if (blk < 4096) {
        int id = blk * 256 + threadIdx.x;    // float4 index over [4096,256]
        int c4 = id & 255;
        float4 va = ((const float4*)C1a)[id];
        float4 vb = ((const float4*)C1b)[id];
        float4 vc = ((const float4*)C1c)[id];
        float vs[4] = {va.x + vb.x + vc.x, va.y + vb.y + vc.y,
                       va.z + vb.z + vc.z, va.w + vb.w + vc.w};
        union { ushort4 u; unsigned short s[4]; } H, L;
#pragma unroll
        for (int q = 0; q < 4; ++q) {
            int col = c4 * 4 + q;
            float bias = (col < 512) ? theta_b[col] : f_b[col - 512];
            float v = vs[q] + bias;
            bf16 h = __float2bfloat16(v);
            float rem = v - __bfloat162float(h);
            bf16 l = __float2bfloat16(rem);
            H.s[q] = *(unsigned short*)&h;
            L.s[q] = *(unsigned short*)&l;
        }
        ((ushort4*)thfHi)[id] = H.u;
        ((ushort4*)thfLo)[id] = L.u;
    } else {
        int bid = blk - 4096;               // 16384 blocks
        int t = threadIdx.x;
        int tx = t & 31, ty = t >> 5;
        int k0 = (bid & 127) * 32;
        int n0 = (bid >> 7) * 32;
#pragma unroll
        for (int r = 0; r < 4; ++r) {
            int k = k0 + ty + r * 8;
            tile[ty + r * 8][tx] = g_w[(size_t)k * 4096 + (n0 + tx)];
        }
        __syncthreads();
#pragma unroll
        for (int r = 0; r < 4; ++r) {
            int n = n0 + ty + r * 8;
            int k = k0 + tx;
            gwt[(size_t)n * 4096 + k] = __float2bfloat16(tile[tx][ty + r * 8]);
        }
    }
}

// ---------------- scores: f/theta swapped MFMA, float4 stores ----------------

__global__ __launch_bounds__(256, 3) void scores(const bf16* __restrict__ thfHi,
                                                 const bf16* __restrict__ thfLo,
                                                 float* __restrict__ S) {
    __shared__ bf16 As[128 * 32];
    __shared__ bf16 Bs[128 * 32];
    int m0 = blockIdx.x * 128;     // q (f index)
    int n0 = blockIdx.y * 128;     // p (theta index)
    int b = blockIdx.z;
    const bf16* Ahi = thfHi + (size_t)b * 256 * 1024;
    const bf16* Alo = thfLo + (size_t)b * 256 * 1024;
    f32x4 acc[4][4] = {};
    gemm_pass(Ahi + 512, Ahi, 1024, 1024, m0, n0, 0, 16, As, Bs, acc);  // f_hi * th_hi
    gemm_pass(Ahi + 512, Alo, 1024, 1024, m0, n0, 0, 16, As, Bs, acc);  // f_hi * th_lo
    gemm_pass(Alo + 512, Ahi, 1024, 1024, m0, n0, 0, 16, As, Bs, acc);  // f_lo * th_hi
    float* Sb = S + (size_t)b * 65536;
    int t = threadIdx.x, lane = t & 63, wave = t >> 6;
    int wm = wave & 1, wn = wave >> 1;
    int lr = lane & 15, lq = lane >> 4;
#pragma unroll
    for (int mt = 0; mt < 4; ++mt) {
        int q = m0 + wm * 64 + mt * 16 + lq * 4;
#pragma unroll
        for (int nt = 0; nt < 4; ++nt) {
            int p = n0 + wn * 64 + nt * 16 + lr;
            *(float4*)(Sb + (size_t)p * 256 + q) = *(float4*)&acc[mt][nt];
        }
    }
}

// ---------------- softmax: one wave per 256-wide row, in place ----------------

__global__ __launch_bounds__(256) void softmax_rows(float* __restrict__ S) {
    int row = blockIdx.x * 4 + (threadIdx.x >> 6);
    int lane = threadIdx.x & 63;
    float4* p = (float4*)(S + (size_t)row * 256);
    float4 v = p[lane];
    float mx = fmaxf(fmaxf(v.x, v.y), fmaxf(v.z, v.w));
#pragma unroll
    for (int s = 32; s >= 1; s >>= 1) mx = fmaxf(mx, __shfl_xor(mx, s, 64));
    v.x = expf(v.x - mx); v.y = expf(v.y - mx);
    v.z = expf(v.z - mx); v.w = expf(v.w - mx);
    float sm = (v.x + v.y) + (v.z + v.w);
#pragma unroll
    for (int s = 32; s >= 1; s >>= 1) sm += __shfl_xor(sm, s, 64);
    float inv = 1.0f / sm;
    v.x *= inv; v.y *= inv; v.z *= inv; v.w *= inv;
    p[lane] = v;
}

// ---------------- gemm2: swapped operands + float4 epilogue ----------------
// A = gwt rows (g-output dim n, 4096), B = pHi rows (patch dim m, 4096).

__global__ __launch_bounds__(256, 3) void gemm2(const bf16* __restrict__ pHi,
                                                const bf16* __restrict__ gwt,
                                                const float* __restrict__ g_b,
                                                const float* __restrict__ wts,
                                                const float* __restrict__ x,
                                                const float* __restrict__ scale,
                                                float* __restrict__ out) {
    __shared__ bf16 As[128 * 32];
    __shared__ bf16 Bs[128 * 32];
    int m0 = blockIdx.x * 128;    // g-output dim
    int n0 = blockIdx.y * 128;    // patch dim
    f32x4 acc[4][4] = {};
    gemm_pass(gwt, pHi, 4096, 4096, m0, n0, 0, 128, As, Bs, acc);
    int t = threadIdx.x, lane = t & 63, wave = t >> 6;
    int wm = wave & 1, wn = wave >> 1;
    int lr = lane & 15, lq = lane >> 4;
    float scl = scale[0];
#pragma unroll
    for (int mt = 0; mt < 4; ++mt) {
        int ng = m0 + wm * 64 + mt * 16 + lq * 4;      // +reg, 4-consecutive
        int cc = ng >> 8;
        int y = (ng >> 4) & 15;
        int zq = ng & 255;
        float4 gb4 = *(const float4*)(g_b + ng);
#pragma unroll
        for (int nt = 0; nt < 4; ++nt) {
            int mg = n0 + wn * 64 + nt * 16 + lr;       // b*256 + pi
            int bb = mg >> 8, pi = mg & 255;
            int i = pi >> 4, j = pi & 15;
            float4 wt4 = *(const float4*)(wts + (size_t)mg * 256 + zq);
            size_t idx = ((((size_t)(bb * 16 + cc)) * 256) + i * 16 + y) * 256
                         + j * 16 + (ng & 15);
            float4 xv = *(const float4*)(x + idx);
            f32x4 a = acc[mt][nt];
            float4 o;
            o.x = scl * wt4.x * (a[0] + gb4.x) + xv.x;
            o.y = scl * wt4.y * (a[1] + gb4.y) + xv.y;
            o.z = scl * wt4.z * (a[2] + gb4.z) + xv.z;
            o.w = scl * wt4.w * (a[3] + gb4.w) + xv.w;
            *(float4*)(out + idx) = o;
        }
    }
}

// ---------------- launch ----------------

extern "C" void kernel_launch(void* const* d_in, const int* in_sizes, int n_in,
                              void* d_out, int out_size, void* d_ws, size_t ws_size,
                              hipStream_t stream) {
    const float* x       = (const float*)d_in[0];
    const float* theta_w = (const float*)d_in[1];
    const float* theta_b = (const float*)d_in[2];
    const float* f_w     = (const float*)d_in[3];
    const float* f_b     = (const float*)d_in[4];
    const float* g_w     = (const float*)d_in[5];
    const float* g_b     = (const float*)d_in[6];
    const float* scale   = (const float*)d_in[7];
    (void)in_sizes; (void)n_in; (void)out_size; (void)ws_size;

    const size_t MiB = 1048576;
    char* ws = (char*)d_ws;
    bf16*  pHi   = (bf16*)(ws);                     // [0,32) live whole run
    bf16*  pLo   = (bf16*)(ws + 32 * MiB);          // [32,64) dead after gemm1f
    bf16*  gwt   = (bf16*)(ws + 32 * MiB);          //   reuse after gemm1f
    bf16*  wHi   = (bf16*)(ws + 64 * MiB);          // [64,72) dead after gemm1f
    bf16*  wLo   = (bf16*)(ws + 72 * MiB);          // [72,80) dead after gemm1f
    bf16*  thfHi = (bf16*)(ws + 64 * MiB);          //   reuse: [64,72)
    bf16*  thfLo = (bf16*)(ws + 72 * MiB);          //   reuse: [72,80)
    float* C1a   = (float*)(ws + 80 * MiB);         // [80,96) dead after combine
    float* S     = (float*)(ws + 80 * MiB);         //   reuse: [80,84)
    float* C1b   = (float*)(ws + 96 * MiB);         // [96,112) dead after combine
    float* C1c   = (float*)(ws + 112 * MiB);        // [112,128) dead after combine

    prep_pw<<<20480, 256, 0, stream>>>(x, theta_w, f_w, pHi, pLo, wHi, wLo);
    gemm1f<<<dim3(8, 32, 3), 256, 0, stream>>>(pHi, pLo, wHi, wLo, C1a, C1b, C1c);
    combine_prepg<<<20480, 256, 0, stream>>>(C1a, C1b, C1c, theta_b, f_b, g_w,
                                             thfHi, thfLo, gwt);
    scores<<<dim3(2, 2, 16), 256, 0, stream>>>(thfHi, thfLo, S);
    softmax_rows<<<1024, 256, 0, stream>>>(S);
    gemm2<<<dim3(32, 32), 256, 0, stream>>>(pHi, gwt, g_b, S, x, scale, (float*)d_out);
}

// Round 6
// 526.965 us; speedup vs baseline: 1.0415x; 1.0415x over previous
//
#include <hip/hip_runtime.h>
#include <hip/hip_bf16.h>
#include <stdint.h>

// LocalEnhancementModule on MI355X (gfx950).
// B=16 C=16 H=W=256 NP=16 -> P=256, D=4096, E=512, M=B*P=4096.
//  prep_pw : x -> p_hi/p_lo bf16 [M,D]  +  [theta_w|f_w] -> w hi/lo [1024,D]
//  gemm1f  : fused 3-product hi/lo bf16 MFMA, split-K x2 -> C1a/C1b fp32 [M,1024]
//  combine_prepg : C1a+C1b+bias -> thf hi/lo bf16; also g_w -> gwt bf16
//  scores  : 3-pass hi/lo MFMA theta@f^T -> S fp32 [16,256,256]
//  softmax_rows : in-place row softmax on S
//  gemm2   : bf16 MFMA, A=gwt rows, B=pHi rows; float4 epilogue; bound (256,4)
//            out = scale*w*(acc+g_b) + x
//
// Workspace (lifetime-packed, max 112 MiB):
//  pHi [0,32) | pLo->gwt [32,64) | wHi/wLo [64,80) -> thfHi/thfLo after gemm1f
//  C1a->S [80,96) | C1b [96,112)

typedef __hip_bfloat16 bf16;
typedef __bf16 bf16x8 __attribute__((ext_vector_type(8)));
typedef float f32x4 __attribute__((ext_vector_type(4)));

#define GLOBAL_AS __attribute__((address_space(1)))
#define LDS_AS __attribute__((address_space(3)))

__device__ __forceinline__ void gload_lds16(const void* g, void* l) {
    void* gg = const_cast<void*>(g);
    __builtin_amdgcn_global_load_lds((GLOBAL_AS void*)gg, (LDS_AS void*)l, 16, 0, 0);
}

// ---------------- merged prep: p (hi/lo) + w (hi/lo transposed) ----------------

__global__ __launch_bounds__(256) void prep_pw(const float* __restrict__ x,
                                               const float* __restrict__ theta_w,
                                               const float* __restrict__ f_w,
                                               bf16* __restrict__ pHi,
                                               bf16* __restrict__ pLo,
                                               bf16* __restrict__ wHi,
                                               bf16* __restrict__ wLo) {
    __shared__ float tile[32][33];
    int blk = blockIdx.x;
    if (blk < 16384) {
        int tid = blk * 256 + threadIdx.x;           // over [B][C][H][W/4]
        int w4 = tid & 63;
        int h  = (tid >> 6) & 255;
        int c  = (tid >> 14) & 15;
        int b  = tid >> 18;
        float4 v = ((const float4*)x)[tid];
        int i = h >> 4, y = h & 15, j = w4 >> 2, zb = (w4 & 3) * 4;
        int m = b * 256 + i * 16 + j;
        int k = c * 256 + y * 16 + zb;
        size_t o = (size_t)m * 4096 + k;
        float vs[4] = {v.x, v.y, v.z, v.w};
#pragma unroll
        for (int q = 0; q < 4; ++q) {
            bf16 hv = __float2bfloat16(vs[q]);
            float rem = vs[q] - __bfloat162float(hv);
            pHi[o + q] = hv;
            pLo[o + q] = __float2bfloat16(rem);
        }
    } else {
        int bid = blk - 16384;                       // 4096 blocks
        int t = threadIdx.x;
        int tx = t & 31, ty = t >> 5;
        int k0 = (bid & 127) * 32;
        int e0 = (bid >> 7) * 32;
#pragma unroll
        for (int r = 0; r < 4; ++r) {
            int k = k0 + ty + r * 8;
            int e = e0 + tx;
            float v = (e < 512) ? theta_w[(size_t)k * 512 + e]
                                : f_w[(size_t)k * 512 + (e - 512)];
            tile[ty + r * 8][tx] = v;
        }
        __syncthreads();
#pragma unroll
        for (int r = 0; r < 4; ++r) {
            int e = e0 + ty + r * 8;
            int k = k0 + tx;
            float v = tile[tx][ty + r * 8];
            bf16 hv = __float2bfloat16(v);
            float rem = v - __bfloat162float(hv);
            wHi[(size_t)e * 4096 + k] = hv;
            wLo[(size_t)e * 4096 + k] = __float2bfloat16(rem);
        }
    }
}

// ---------------- generic GEMM pass (scores / gemm2) ----------------
// BM=BN=128, BK=32, 256 threads (4 waves, 2x2 wave grid, 64x64/wave).
__device__ __forceinline__ void gemm_pass(const bf16* A, const bf16* Bt,
                                          int lda, int ldb, int m0, int n0,
                                          int kbase, int ksteps,
                                          bf16* As, bf16* Bs, f32x4 (&acc)[4][4]) {
    int t = threadIdx.x, lane = t & 63, wave = t >> 6;
    int wm = wave & 1, wn = wave >> 1;
    int lr = lane & 15, lq = lane >> 4;
    const bf16* gA = A + (size_t)m0 * lda;
    const bf16* gB = Bt + (size_t)n0 * ldb;
    int chunk0 = wave * 2;
    int srow0 = lane >> 2;
    int cb = (lane & 3) * 16;
    for (int ks = 0; ks < ksteps; ++ks) {
        int kt = kbase + ks * 32;
#pragma unroll
        for (int tt = 0; tt < 2; ++tt) {
            int chunk = chunk0 + tt;
            int row = chunk * 16 + srow0;
            gload_lds16((const char*)(gA + ((size_t)row * lda + kt)) + cb,
                        (char*)As + chunk * 1024);
            gload_lds16((const char*)(gB + ((size_t)row * ldb + kt)) + cb,
                        (char*)Bs + chunk * 1024);
        }
        __syncthreads();
        bf16x8 af[4], bfr[4];
#pragma unroll
        for (int mt = 0; mt < 4; ++mt)
            af[mt] = *(const bf16x8*)((const char*)As + (wm * 64 + mt * 16 + lr) * 64 + lq * 16);
#pragma unroll
        for (int nt = 0; nt < 4; ++nt)
            bfr[nt] = *(const bf16x8*)((const char*)Bs + (wn * 64 + nt * 16 + lr) * 64 + lq * 16);
#pragma unroll
        for (int mt = 0; mt < 4; ++mt)
#pragma unroll
            for (int nt = 0; nt < 4; ++nt)
                acc[mt][nt] = __builtin_amdgcn_mfma_f32_16x16x32_bf16(
                    af[mt], bfr[nt], acc[mt][nt], 0, 0, 0);
        __syncthreads();
    }
}

// ---------------- gemm1f: fused 3-product hi/lo, split-K x2, swapped ----------------
// A = w rows (e-dim, 1024), B = p rows (patch dim, 4096).

__global__ __launch_bounds__(256) void gemm1f(const bf16* __restrict__ pHi,
                                              const bf16* __restrict__ pLo,
                                              const bf16* __restrict__ wHi,
                                              const bf16* __restrict__ wLo,
                                              float* __restrict__ C1a,
                                              float* __restrict__ C1b) {
    __shared__ bf16 AsHi[128 * 32];
    __shared__ bf16 AsLo[128 * 32];
    __shared__ bf16 BsHi[128 * 32];
    __shared__ bf16 BsLo[128 * 32];
    int m0 = blockIdx.x * 128;      // e-dim
    int n0 = blockIdx.y * 128;      // patch dim
    int kbase = blockIdx.z * 2048;
    int t = threadIdx.x, lane = t & 63, wave = t >> 6;
    int wm = wave & 1, wn = wave >> 1;
    int lr = lane & 15, lq = lane >> 4;
    const bf16* gAh = wHi + (size_t)m0 * 4096;
    const bf16* gAl = wLo + (size_t)m0 * 4096;
    const bf16* gBh = pHi + (size_t)n0 * 4096;
    const bf16* gBl = pLo + (size_t)n0 * 4096;
    int chunk0 = wave * 2;
    int srow0 = lane >> 2;
    int cb = (lane & 3) * 16;
    f32x4 acc[4][4] = {};
    for (int ks = 0; ks < 64; ++ks) {
        int kt = kbase + ks * 32;
#pragma unroll
        for (int tt = 0; tt < 2; ++tt) {
            int chunk = chunk0 + tt;
            size_t off = (size_t)(chunk * 16 + srow0) * 4096 + kt;
            gload_lds16((const char*)(gAh + off) + cb, (char*)AsHi + chunk * 1024);
            gload_lds16((const char*)(gAl + off) + cb, (char*)AsLo + chunk * 1024);
            gload_lds16((const char*)(gBh + off) + cb, (char*)BsHi + chunk * 1024);
            gload_lds16((const char*)(gBl + off) + cb, (char*)BsLo + chunk * 1024);
        }
        __syncthreads();
        bf16x8 ah[4], al[4], bh[4], bl[4];
#pragma unroll
        for (int mt = 0; mt < 4; ++mt) {
            int ro = (wm * 64 + mt * 16 + lr) * 64 + lq * 16;
            ah[mt] = *(const bf16x8*)((const char*)AsHi + ro);
            al[mt] = *(const bf16x8*)((const char*)AsLo + ro);
        }
#pragma unroll
        for (int nt = 0; nt < 4; ++nt) {
            int ro = (wn * 64 + nt * 16 + lr) * 64 + lq * 16;
            bh[nt] = *(const bf16x8*)((const char*)BsHi + ro);
            bl[nt] = *(const bf16x8*)((const char*)BsLo + ro);
        }
#pragma unroll
        for (int mt = 0; mt < 4; ++mt)
#pragma unroll
            for (int nt = 0; nt < 4; ++nt)
                acc[mt][nt] = __builtin_amdgcn_mfma_f32_16x16x32_bf16(
                    ah[mt], bl[nt], acc[mt][nt], 0, 0, 0);
#pragma unroll
        for (int mt = 0; mt < 4; ++mt)
#pragma unroll
            for (int nt = 0; nt < 4; ++nt)
                acc[mt][nt] = __builtin_amdgcn_mfma_f32_16x16x32_bf16(
                    al[mt], bh[nt], acc[mt][nt], 0, 0, 0);
#pragma unroll
        for (int mt = 0; mt < 4; ++mt)
#pragma unroll
            for (int nt = 0; nt < 4; ++nt)
                acc[mt][nt] = __builtin_amdgcn_mfma_f32_16x16x32_bf16(
                    ah[mt], bh[nt], acc[mt][nt], 0, 0, 0);
        __syncthreads();
    }
    float* C = blockIdx.z ? C1b : C1a;
#pragma unroll
    for (int mt = 0; mt < 4; ++mt) {
        int e = m0 + wm * 64 + mt * 16 + lq * 4;       // +reg, 4-consecutive
#pragma unroll
        for (int nt = 0; nt < 4; ++nt) {
            int p = n0 + wn * 64 + nt * 16 + lr;
            *(float4*)(C + (size_t)p * 1024 + e) = *(float4*)&acc[mt][nt];
        }
    }
}

// ---------------- combine + prep_g merged ----------------

__global__ __launch_bounds__(256) void combine_prepg(const float* __restrict__ C1a,
                                                     const float* __restrict__ C1b,
                                                     const float* __restrict__ theta_b,
                                                     const float* __restrict__ f_b,
                                                     const float* __restrict__ g_w,
                                                     bf16* __restrict__ thfHi,
                                                     bf16* __restrict__ thfLo,
                                                     bf16* __restrict__ gwt) {
    __shared__ float tile[32][33];
    int blk = blockIdx.x;
    if (blk < 4096) {
        int id = blk * 256 + threadIdx.x;    // float4 index over [4096,256]
        int c4 = id & 255;
        float4 va = ((const float4*)C1a)[id];
        float4 vb = ((const float4*)C1b)[id];
        float vs[4] = {va.x + vb.x, va.y + vb.y, va.z + vb.z, va.w + vb.w};
        union { ushort4 u; unsigned short s[4]; } H, L;
#pragma unroll
        for (int q = 0; q < 4; ++q) {
            int col = c4 * 4 + q;
            float bias = (col < 512) ? theta_b[col] : f_b[col - 512];
            float v = vs[q] + bias;
            bf16 h = __float2bfloat16(v);
            float rem = v - __bfloat162float(h);
            bf16 l = __float2bfloat16(rem);
            H.s[q] = *(unsigned short*)&h;
            L.s[q] = *(unsigned short*)&l;
        }
        ((ushort4*)thfHi)[id] = H.u;
        ((ushort4*)thfLo)[id] = L.u;
    } else {
        int bid = blk - 4096;               // 16384 blocks
        int t = threadIdx.x;
        int tx = t & 31, ty = t >> 5;
        int k0 = (bid & 127) * 32;
        int n0 = (bid >> 7) * 32;
#pragma unroll
        for (int r = 0; r < 4; ++r) {
            int k = k0 + ty + r * 8;
            tile[ty + r * 8][tx] = g_w[(size_t)k * 4096 + (n0 + tx)];
        }
        __syncthreads();
#pragma unroll
        for (int r = 0; r < 4; ++r) {
            int n = n0 + ty + r * 8;
            int k = k0 + tx;
            gwt[(size_t)n * 4096 + k] = __float2bfloat16(tile[tx][ty + r * 8]);
        }
    }
}

// ---------------- scores: f/theta swapped MFMA, float4 stores ----------------

__global__ __launch_bounds__(256, 3) void scores(const bf16* __restrict__ thfHi,
                                                 const bf16* __restrict__ thfLo,
                                                 float* __restrict__ S) {
    __shared__ bf16 As[128 * 32];
    __shared__ bf16 Bs[128 * 32];
    int m0 = blockIdx.x * 128;     // q (f index)
    int n0 = blockIdx.y * 128;     // p (theta index)
    int b = blockIdx.z;
    const bf16* Ahi = thfHi + (size_t)b * 256 * 1024;
    const bf16* Alo = thfLo + (size_t)b * 256 * 1024;
    f32x4 acc[4][4] = {};
    gemm_pass(Ahi + 512, Ahi, 1024, 1024, m0, n0, 0, 16, As, Bs, acc);  // f_hi * th_hi
    gemm_pass(Ahi + 512, Alo, 1024, 1024, m0, n0, 0, 16, As, Bs, acc);  // f_hi * th_lo
    gemm_pass(Alo + 512, Ahi, 1024, 1024, m0, n0, 0, 16, As, Bs, acc);  // f_lo * th_hi
    float* Sb = S + (size_t)b * 65536;
    int t = threadIdx.x, lane = t & 63, wave = t >> 6;
    int wm = wave & 1, wn = wave >> 1;
    int lr = lane & 15, lq = lane >> 4;
#pragma unroll
    for (int mt = 0; mt < 4; ++mt) {
        int q = m0 + wm * 64 + mt * 16 + lq * 4;
#pragma unroll
        for (int nt = 0; nt < 4; ++nt) {
            int p = n0 + wn * 64 + nt * 16 + lr;
            *(float4*)(Sb + (size_t)p * 256 + q) = *(float4*)&acc[mt][nt];
        }
    }
}

// ---------------- softmax: one wave per 256-wide row, in place ----------------

__global__ __launch_bounds__(256) void softmax_rows(float* __restrict__ S) {
    int row = blockIdx.x * 4 + (threadIdx.x >> 6);
    int lane = threadIdx.x & 63;
    float4* p = (float4*)(S + (size_t)row * 256);
    float4 v = p[lane];
    float mx = fmaxf(fmaxf(v.x, v.y), fmaxf(v.z, v.w));
#pragma unroll
    for (int s = 32; s >= 1; s >>= 1) mx = fmaxf(mx, __shfl_xor(mx, s, 64));
    v.x = expf(v.x - mx); v.y = expf(v.y - mx);
    v.z = expf(v.z - mx); v.w = expf(v.w - mx);
    float sm = (v.x + v.y) + (v.z + v.w);
#pragma unroll
    for (int s = 32; s >= 1; s >>= 1) sm += __shfl_xor(sm, s, 64);
    float inv = 1.0f / sm;
    v.x *= inv; v.y *= inv; v.z *= inv; v.w *= inv;
    p[lane] = v;
}

// ---------------- gemm2: swapped operands + float4 epilogue, 4 blocks/CU ----------------
// A = gwt rows (g-output dim n, 4096), B = pHi rows (patch dim m, 4096).

__global__ __launch_bounds__(256, 4) void gemm2(const bf16* __restrict__ pHi,
                                                const bf16* __restrict__ gwt,
                                                const float* __restrict__ g_b,
                                                const float* __restrict__ wts,
                                                const float* __restrict__ x,
                                                const float* __restrict__ scale,
                                                float* __restrict__ out) {
    __shared__ bf16 As[128 * 32];
    __shared__ bf16 Bs[128 * 32];
    int m0 = blockIdx.x * 128;    // g-output dim
    int n0 = blockIdx.y * 128;    // patch dim
    f32x4 acc[4][4] = {};
    gemm_pass(gwt, pHi, 4096, 4096, m0, n0, 0, 128, As, Bs, acc);
    int t = threadIdx.x, lane = t & 63, wave = t >> 6;
    int wm = wave & 1, wn = wave >> 1;
    int lr = lane & 15, lq = lane >> 4;
    float scl = scale[0];
#pragma unroll
    for (int mt = 0; mt < 4; ++mt) {
        int ng = m0 + wm * 64 + mt * 16 + lq * 4;      // +reg, 4-consecutive
        int cc = ng >> 8;
        int y = (ng >> 4) & 15;
        int zq = ng & 255;
        float4 gb4 = *(const float4*)(g_b + ng);
#pragma unroll
        for (int nt = 0; nt < 4; ++nt) {
            int mg = n0 + wn * 64 + nt * 16 + lr;       // b*256 + pi
            int bb = mg >> 8, pi = mg & 255;
            int i = pi >> 4, j = pi & 15;
            float4 wt4 = *(const float4*)(wts + (size_t)mg * 256 + zq);
            size_t idx = ((((size_t)(bb * 16 + cc)) * 256) + i * 16 + y) * 256
                         + j * 16 + (ng & 15);
            float4 xv = *(const float4*)(x + idx);
            f32x4 a = acc[mt][nt];
            float4 o;
            o.x = scl * wt4.x * (a[0] + gb4.x) + xv.x;
            o.y = scl * wt4.y * (a[1] + gb4.y) + xv.y;
            o.z = scl * wt4.z * (a[2] + gb4.z) + xv.z;
            o.w = scl * wt4.w * (a[3] + gb4.w) + xv.w;
            *(float4*)(out + idx) = o;
        }
    }
}

// ---------------- launch ----------------

extern "C" void kernel_launch(void* const* d_in, const int* in_sizes, int n_in,
                              void* d_out, int out_size, void* d_ws, size_t ws_size,
                              hipStream_t stream) {
    const float* x       = (const float*)d_in[0];
    const float* theta_w = (const float*)d_in[1];
    const float* theta_b = (const float*)d_in[2];
    const float* f_w     = (const float*)d_in[3];
    const float* f_b     = (const float*)d_in[4];
    const float* g_w     = (const float*)d_in[5];
    const float* g_b     = (const float*)d_in[6];
    const float* scale   = (const float*)d_in[7];
    (void)in_sizes; (void)n_in; (void)out_size; (void)ws_size;

    const size_t MiB = 1048576;
    char* ws = (char*)d_ws;
    bf16*  pHi   = (bf16*)(ws);                     // [0,32) live whole run
    bf16*  pLo   = (bf16*)(ws + 32 * MiB);          // [32,64) dead after gemm1f
    bf16*  gwt   = (bf16*)(ws + 32 * MiB);          //   reuse after gemm1f
    bf16*  wHi   = (bf16*)(ws + 64 * MiB);          // [64,72) dead after gemm1f
    bf16*  wLo   = (bf16*)(ws + 72 * MiB);          // [72,80) dead after gemm1f
    bf16*  thfHi = (bf16*)(ws + 64 * MiB);          //   reuse: [64,72)
    bf16*  thfLo = (bf16*)(ws + 72 * MiB);          //   reuse: [72,80)
    float* C1a   = (float*)(ws + 80 * MiB);         // [80,96) dead after combine
    float* S     = (float*)(ws + 80 * MiB);         //   reuse: [80,84)
    float* C1b   = (float*)(ws + 96 * MiB);         // [96,112) dead after combine

    prep_pw<<<20480, 256, 0, stream>>>(x, theta_w, f_w, pHi, pLo, wHi, wLo);
    gemm1f<<<dim3(8, 32, 2), 256, 0, stream>>>(pHi, pLo, wHi, wLo, C1a, C1b);
    combine_prepg<<<20480, 256, 0, stream>>>(C1a, C1b, theta_b, f_b, g_w,
                                             thfHi, thfLo, gwt);
    scores<<<dim3(2, 2, 16), 256, 0, stream>>>(thfHi, thfLo, S);
    softmax_rows<<<1024, 256, 0, stream>>>(S);
    gemm2<<<dim3(32, 32), 256, 0, stream>>>(pHi, gwt, g_b, S, x, scale, (float*)d_out);
}